// Round 4
// baseline (34.853 us; speedup 1.0000x reference)
//
#include <hip/hip_runtime.h>
#include <math.h>

// Fused plan+sample for TemporalSamplingUpSampler, 1-barrier plan.
// out[0, c, t] = A[c, seg(t)] * w(t); C=256, K=256, T=131072 (from in_sizes).
//
// Each WAVE redundantly computes the full K=256 plan with zero cross-wave
// communication (4 entries per lane, shfl reductions/scan):
//   Lp = f32( T * exp(L-max) / sum )  in double (jax f32 softmax proxy)
//   l_max = int(max(Lp)+0.5) = int(f64(f32(T/S))+0.5)   [argmax term has e=1]
//   r = max(rint(Lp),0); cumsum via in-lane prefix + shfl_up scan
// Wave 0 publishes cumsum + scale tables to LDS (needed for bsearch's random
// access), ONE barrier, then every lane derives its own 4 (seg, w) in regs.
// Store phase: 256 cols x C channels, NT float4 stores, unroll 8.

#define KFIX 256

typedef float f32x4 __attribute__((ext_vector_type(4)));

__global__ __launch_bounds__(256) void fused_kernel(const float* __restrict__ A,
                                                    const float* __restrict__ L,
                                                    float* __restrict__ out,
                                                    int K, int C, int T) {
    __shared__ int   s_c1[KFIX];   // c1[k] = cum[k+1] = sum_{i<=k} r_i
    __shared__ float s_s[KFIX];    // l_max / Lp
    __shared__ float s_tl[KFIX];   // (l_max - Lp) / Lp

    const int tid  = threadIdx.x;
    const int lane = tid & 63;
    const int cs   = tid >> 6;
    const int k4   = lane * 4;

    // ---- wave-redundant plan (no barriers until publish) ----
    const f32x4 Lv = *(const f32x4*)(L + k4);

    float m = fmaxf(fmaxf(Lv.x, Lv.y), fmaxf(Lv.z, Lv.w));
    #pragma unroll
    for (int o = 32; o > 0; o >>= 1) m = fmaxf(m, __shfl_xor(m, o));
    const double md = (double)m;

    const double e0 = exp((double)Lv.x - md);
    const double e1 = exp((double)Lv.y - md);
    const double e2 = exp((double)Lv.z - md);
    const double e3 = exp((double)Lv.w - md);
    double se = (e0 + e1) + (e2 + e3);
    #pragma unroll
    for (int o = 32; o > 0; o >>= 1) se += __shfl_xor(se, o);
    const double S  = se;
    const double Td = (double)T;

    const float Lp0 = (float)(Td * e0 / S);
    const float Lp1 = (float)(Td * e1 / S);
    const float Lp2 = (float)(Td * e2 / S);
    const float Lp3 = (float)(Td * e3 / S);

    // max(Lp) = f32(T/S): the argmax entry has exp(0) == 1 exactly.
    const int l_max = (int)((double)((float)(Td / S)) + 0.5);
    const float fl  = (float)l_max;

    const int r0 = max((int)rintf(Lp0), 0);
    const int r1 = max((int)rintf(Lp1), 0);
    const int r2 = max((int)rintf(Lp2), 0);
    const int r3 = max((int)rintf(Lp3), 0);

    const int p0 = r0, p1 = p0 + r1, p2 = p1 + r2, p3 = p2 + r3;
    int inc = p3;
    #pragma unroll
    for (int o = 1; o < 64; o <<= 1) {
        const int n = __shfl_up(inc, o);
        if (lane >= o) inc += n;
    }
    const int total = __shfl(inc, 63);
    const int excl  = inc - p3;

    if (tid < 64) {          // wave 0 publishes
        s_c1[k4 + 0] = excl + p0;
        s_c1[k4 + 1] = excl + p1;
        s_c1[k4 + 2] = excl + p2;
        s_c1[k4 + 3] = excl + p3;
        s_s [k4 + 0] = fl / Lp0;
        s_s [k4 + 1] = fl / Lp1;
        s_s [k4 + 2] = fl / Lp2;
        s_s [k4 + 3] = fl / Lp3;
        s_tl[k4 + 0] = (fl - Lp0) / Lp0;
        s_tl[k4 + 1] = (fl - Lp1) / Lp1;
        s_tl[k4 + 2] = (fl - Lp2) / Lp2;
        s_tl[k4 + 3] = (fl - Lp3) / Lp3;
    }
    __syncthreads();         // the only barrier

    // ---- per-lane: 4 columns' (seg, w) in registers ----
    const int    t0    = blockIdx.x * 256;
    const double ratio = (double)total / Td;
    int   seg[4];
    float w[4];
    #pragma unroll
    for (int u = 0; u < 4; ++u) {
        const int t = t0 + k4 + u;
        int   sg = 0;
        float ww = 0.0f;
        if (t < T) {
            int j = (int)floor((double)t * ratio);
            if (j > total - 1) j = total - 1;
            if (j < 0) j = 0;
            int lo = 0, hi = KFIX - 1;
            while (lo < hi) {
                const int mid = (lo + hi) >> 1;
                if (s_c1[mid] > j) hi = mid; else lo = mid + 1;
            }
            sg = lo;
            const int loc = j - (lo ? s_c1[lo - 1] : 0);
            const float x  = (2.0f * (float)loc + 1.0f) / fl - 1.0f;
            const float xs = s_s[lo] * x + s_tl[lo];
            const float p  = ((xs + 1.0f) * 100.0f - 1.0f) * 0.5f;
            const float pf = floorf(p);
            const float w1 = p - pf;
            if (pf >= 0.0f  && pf <= 99.0f) ww += 1.0f - w1;
            if (pf >= -1.0f && pf <= 98.0f) ww += w1;
        }
        seg[u] = sg;
        w[u]   = ww;
    }

    // ---- stream 256 cols x C channels: NT float4 along t, 4 ch-rows/pass ----
    const int tq = t0 + k4;

    if (tq + 3 < T) {
        #pragma unroll 8
        for (int cb = 0; cb < C; cb += 4) {
            const int c = cb + cs;
            const float* __restrict__ Ar = A + (size_t)c * K;
            f32x4 vv;
            vv.x = Ar[seg[0]] * w[0];
            vv.y = Ar[seg[1]] * w[1];
            vv.z = Ar[seg[2]] * w[2];
            vv.w = Ar[seg[3]] * w[3];
            __builtin_nontemporal_store(vv, (f32x4*)(out + (size_t)c * T + tq));
        }
    } else {
        for (int cb = 0; cb < C; cb += 4) {
            const int c = cb + cs;
            const float* __restrict__ Ar = A + (size_t)c * K;
            for (int u = 0; u < 4; ++u) {
                const int t = tq + u;
                if (t < T) out[(size_t)c * T + t] = Ar[seg[u]] * w[u];
            }
        }
    }
}

extern "C" void kernel_launch(void* const* d_in, const int* in_sizes, int n_in,
                              void* d_out, int out_size, void* d_ws, size_t ws_size,
                              hipStream_t stream) {
    const float* A = (const float*)d_in[0];
    const float* L = (const float*)d_in[1];

    const int K = in_sizes[1];                 // 256 (plan path assumes this)
    const int C = in_sizes[0] / K;             // 256
    const int T = out_size / C;                // 131072

    const int nblk = (T + 255) / 256;
    fused_kernel<<<nblk, 256, 0, stream>>>(A, L, (float*)d_out, K, C, T);
}